// Round 2
// baseline (2075.120 us; speedup 1.0000x reference)
//
#include <hip/hip_runtime.h>

typedef unsigned short u16;
typedef __attribute__((ext_vector_type(8))) short bf16x8;
typedef __attribute__((ext_vector_type(4))) short bf16x4;
typedef __attribute__((ext_vector_type(4))) float f32x4;

#define MFMA16(a, b, c) __builtin_amdgcn_mfma_f32_16x16x32_bf16((a), (b), (c), 0, 0, 0)

// workspace layout (u16 element offsets)
#define OFF_UPAD 0
#define OFF_KS0  589824
#define OFF_W0   851968
#define OFF_W1   983040
#define OFF_W2   1114112
#define OFF_CRT  1179648
#define OFF_P    1196032     // 65 x 65536 (A^t, t=0..64, row-major, bf16)
#define OS_OFF   134479872   // 513*1024*256

__device__ __forceinline__ u16 f2bf(float f) {
  union { float f; unsigned int i; } v; v.f = f;
  return (u16)((v.i + 0x7fffu + ((v.i >> 16) & 1u)) >> 16);
}
__device__ __forceinline__ float bf2f(u16 u) {
  union { unsigned int i; float f; } v; v.i = ((unsigned int)u) << 16;
  return v.f;
}
__device__ __forceinline__ float fast_tanh(float x) {
  float e = __expf(2.0f * x);
  return 1.0f - __fdividef(2.0f, e + 1.0f);
}

// ---------------- prep: bf16 conversions + P0/P1 ----------------
__global__ void k_prep(const float* __restrict__ KS_ALL, const float* __restrict__ next_vf,
                       const float* __restrict__ A_w, const float* __restrict__ W0,
                       const float* __restrict__ W1, const float* __restrict__ W2,
                       u16* __restrict__ ws) {
  int idx = blockIdx.x * 256 + threadIdx.x;
  if (idx < 589824) {  // u_pad[1024][576]: first 64 cols zero, then next_vf row
    int r = idx / 576, c = idx % 576;
    ws[OFF_UPAD + idx] = (c < 64) ? (u16)0 : f2bf(next_vf[r * 512 + c - 64]);
    return;
  }
  idx -= 589824;
  if (idx < 262144) { ws[OFF_KS0 + idx] = f2bf(KS_ALL[idx]); return; }
  idx -= 262144;
  if (idx < 131072) { ws[OFF_W0 + idx] = f2bf(W0[idx]); return; }
  idx -= 131072;
  if (idx < 131072) { ws[OFF_W1 + idx] = f2bf(W1[idx]); return; }
  idx -= 131072;
  if (idx < 65536)  { ws[OFF_W2 + idx] = f2bf(W2[idx]); return; }
  idx -= 65536;
  if (idx < 65536) { // P0 = I, P1 = A
    int r = idx >> 8, c = idx & 255;
    ws[OFF_P + idx] = (r == c) ? (u16)0x3F80 : (u16)0;
    ws[OFF_P + 65536 + idx] = f2bf(A_w[idx]);
  }
}

// ---------------- power doubling: P_{s+j} = P_s @ P_j, j=1..s ----------------
__global__ __launch_bounds__(512) void k_pow(u16* __restrict__ ws, int s) {
  const u16* P = ws + OFF_P;
  int j = blockIdx.y + 1;
  int mh = blockIdx.x;
  int lane = threadIdx.x & 63, w = threadIdx.x >> 6;
  int wm = w >> 2, wn = w & 3;
  int lg = lane >> 4, ll = lane & 15;
  const u16* Am = P + s * 65536;
  const u16* Bm = P + j * 65536;
  f32x4 acc[4][4];
  f32x4 z = {0.f, 0.f, 0.f, 0.f};
#pragma unroll
  for (int mi = 0; mi < 4; ++mi)
#pragma unroll
    for (int ni = 0; ni < 4; ++ni) acc[mi][ni] = z;
#pragma unroll
  for (int ks = 0; ks < 8; ++ks) {
    bf16x8 a[4], b[4];
    int kk = ks * 32 + lg * 8;
#pragma unroll
    for (int mi = 0; mi < 4; ++mi) {
      int row = mh * 128 + wm * 64 + mi * 16 + ll;
      a[mi] = *(const bf16x8*)(Am + row * 256 + kk);
    }
#pragma unroll
    for (int ni = 0; ni < 4; ++ni) {
      int col = wn * 64 + ni * 16 + ll;
#pragma unroll
      for (int e = 0; e < 8; ++e) b[ni][e] = (short)Bm[(kk + e) * 256 + col];
    }
#pragma unroll
    for (int mi = 0; mi < 4; ++mi)
#pragma unroll
      for (int ni = 0; ni < 4; ++ni) acc[mi][ni] = MFMA16(a[mi], b[ni], acc[mi][ni]);
  }
  u16* Pd = ws + OFF_P + (s + j) * 65536;
#pragma unroll
  for (int mi = 0; mi < 4; ++mi)
#pragma unroll
    for (int ni = 0; ni < 4; ++ni)
#pragma unroll
      for (int r = 0; r < 4; ++r) {
        int row = mh * 128 + wm * 64 + mi * 16 + lg * 4 + r;
        int col = wn * 64 + ni * 16 + ll;
        Pd[row * 256 + col] = f2bf(acc[mi][ni][r]);
      }
}

// ---------------- CrevT[n][s] = c_{63-s}[n], c_r = A^r b ----------------
__global__ void k_crevt(const float* __restrict__ B_w, u16* __restrict__ ws) {
  int s = blockIdx.x;
  int n = threadIdx.x;
  const u16* Pr = ws + OFF_P + (63 - s) * 65536 + n * 256;
  float acc = 0.f;
  for (int k = 0; k < 256; ++k) acc += bf2f(Pr[k]) * B_w[k];
  ws[OFF_CRT + n * 64 + s] = f2bf(acc);
}

// ---------------- GEMM: acc += A_lds(128x256,swz) @ Wg^T, 16-wave 32x64 tiles ----------------
__device__ __forceinline__ void gemm16(f32x4 (&acc)[2][4], const u16* Alds,
                                       const u16* __restrict__ Wg, int ldk,
                                       int lane, int wm, int wn) {
  const int lg = lane >> 4, ll = lane & 15;
#pragma unroll
  for (int ks = 0; ks < 8; ++ks) {
    bf16x8 a[2], b[4];
    int kb = ks * 64 + lg * 16;
#pragma unroll
    for (int mi = 0; mi < 2; ++mi) {
      int rl = wm * 32 + mi * 16 + ll;
      int byt = (rl * 512 + kb) ^ ((rl & 7) << 4);
      a[mi] = *(const bf16x8*)(Alds + (byt >> 1));
    }
#pragma unroll
    for (int ni = 0; ni < 4; ++ni) {
      int n = wn * 64 + ni * 16 + ll;
      b[ni] = *(const bf16x8*)(Wg + n * ldk + ks * 32 + lg * 8);
    }
#pragma unroll
    for (int mi = 0; mi < 2; ++mi)
#pragma unroll
      for (int ni = 0; ni < 4; ++ni) acc[mi][ni] = MFMA16(a[mi], b[ni], acc[mi][ni]);
  }
}

__device__ __forceinline__ void actstore_tanh16(const f32x4 (&acc)[2][4], u16* H,
                                                const float* bias, int lane, int wm, int wn) {
  const int lg = lane >> 4, ll = lane & 15;
#pragma unroll
  for (int mi = 0; mi < 2; ++mi)
#pragma unroll
    for (int ni = 0; ni < 4; ++ni)
#pragma unroll
      for (int r = 0; r < 4; ++r) {
        int rl = wm * 32 + mi * 16 + lg * 4 + r;
        int col = wn * 64 + ni * 16 + ll;
        float v = fast_tanh(acc[mi][ni][r] + bias[col]);
        int byt = (rl * 512 + col * 2) ^ ((rl & 7) << 4);
        H[byt >> 1] = f2bf(v);
      }
}

// ---------------- fused KS-gen + MLP (1024 threads, 16 waves) ----------------
__global__ __launch_bounds__(1024, 4) void k_fused(
    const u16* __restrict__ ws,
    const float* __restrict__ b0, const float* __restrict__ b1,
    const float* __restrict__ lng, const float* __restrict__ lnb,
    const float* __restrict__ b2, const float* __restrict__ W3,
    const float* __restrict__ b3, float* __restrict__ out) {
  __shared__ __align__(16) u16 Xb[32768];            // 128x256 bf16, XOR-swizzled
  __shared__ __align__(16) unsigned char Hraw[66560]; // CrevT stage / f32 [64][260] bounce / bf16 H
  __shared__ float par[2308];
  u16* Hb = (u16*)Hraw;
  float* Hf = (float*)Hraw;

  float* pb0 = par;
  float* pb1 = par + 512;
  float* pg  = par + 768;
  float* pbt = par + 1024;
  float* pb2 = par + 1280;
  float* pW3 = par + 1536;
  float* pb3 = par + 2304;

  const int t = blockIdx.y;     // 0..512
  const int rt = blockIdx.x;    // 0..7
  const int tid = threadIdx.x;
  const int lane = tid & 63, w = tid >> 6;
  const int lg = lane >> 4, ll = lane & 15;

  if (tid < 512) pb0[tid] = b0[tid];
  if (tid < 256) { pb1[tid] = b1[tid]; pg[tid] = lng[tid]; pbt[tid] = lnb[tid]; pb2[tid] = b2[tid]; }
  if (tid < 768) pW3[tid] = W3[tid];
  if (tid < 4) pb3[tid] = (tid < 3) ? b3[tid] : 0.f;

  // stage CrevT (256 n x 64 s bf16) into LDS, XOR-swizzled
  {
    const u16* src = ws + OFF_CRT;
#pragma unroll
    for (int c = 0; c < 2; ++c) {
      int cid = tid * 2 + c;
      int n = cid >> 3, q = cid & 7;
      bf16x8 v = *(const bf16x8*)(src + n * 64 + q * 8);
      int byt = ((n << 7) + (q << 4)) ^ ((n & 7) << 4);
      *(bf16x8*)(Hb + (byt >> 1)) = v;
    }
  }
  __syncthreads();

  // ---- phase 1: wave w -> rows (w>>1)*16..+15, col half (w&1)*128 ----
  f32x4 p1[8];
  {
    const int r16 = w >> 1, nh = w & 1;
    int growA = rt * 128 + r16 * 16 + ll;
    const u16* up = ws + OFF_UPAD + growA * 576 + t + lg * 8;
    bf16x8 aw0, aw1;
#pragma unroll
    for (int e = 0; e < 8; ++e) { aw0[e] = (short)up[e]; aw1[e] = (short)up[32 + e]; }
    bf16x8 ah[8];
    if (t < 64) {
      const u16* kp = ws + OFF_KS0 + growA * 256 + lg * 8;
#pragma unroll
      for (int ks = 0; ks < 8; ++ks) ah[ks] = *(const bf16x8*)(kp + ks * 32);
    }
    const u16* Pt = ws + OFF_P + t * 65536;
#pragma unroll
    for (int ni = 0; ni < 8; ++ni) {
      f32x4 acc = {0.f, 0.f, 0.f, 0.f};
      int n = nh * 128 + ni * 16 + ll;
      int b0y = ((n << 7) + (lg << 4)) ^ ((n & 7) << 4);
      int b1y = ((n << 7) + 64 + (lg << 4)) ^ ((n & 7) << 4);
      acc = MFMA16(aw0, *(const bf16x8*)(Hb + (b0y >> 1)), acc);
      acc = MFMA16(aw1, *(const bf16x8*)(Hb + (b1y >> 1)), acc);
      if (t < 64) {
        const u16* pp = Pt + n * 256 + lg * 8;
#pragma unroll
        for (int ks = 0; ks < 8; ++ks) acc = MFMA16(ah[ks], *(const bf16x8*)(pp + ks * 32), acc);
      }
      p1[ni] = acc;
    }
  }
  __syncthreads();   // CrevT no longer needed

  // ---- KS_pre store (coalesced, nontemporal) + Xb build, 2 chunks of 64 rows ----
#pragma unroll
  for (int ch = 0; ch < 2; ++ch) {
    if ((w >> 3) == ch) {
      int rbase = ((w >> 1) & 3) * 16;
      int nh = w & 1;
#pragma unroll
      for (int ni = 0; ni < 8; ++ni)
#pragma unroll
        for (int r = 0; r < 4; ++r)
          Hf[(rbase + lg * 4 + r) * 260 + nh * 128 + ni * 16 + ll] = p1[ni][r];
    }
    __syncthreads();
    float* ob = out + (size_t)t * 262144 + (size_t)(rt * 128 + ch * 64) * 256;
#pragma unroll
    for (int it = 0; it < 4; ++it) {
      int idx = it * 1024 + tid;
      int row = idx >> 6, c4 = idx & 63;
      f32x4 v = *(const f32x4*)(Hf + row * 260 + c4 * 4);
      __builtin_nontemporal_store(v, (f32x4*)(ob + row * 256 + c4 * 4));
      int rl = ch * 64 + row;
      bf16x4 h;
#pragma unroll
      for (int e = 0; e < 4; ++e) h[e] = (short)f2bf(v[e]);
      int byt = (((rl << 9) + ((c4 >> 1) << 4)) ^ ((rl & 7) << 4)) + ((c4 & 1) << 3);
      *(bf16x4*)(Xb + (byt >> 1)) = h;
    }
    __syncthreads();
  }

  // ---- phase 2: MLP, 16 waves of 32x64 tiles ----
  const u16* W0b = ws + OFF_W0;
  const u16* W1b = ws + OFF_W1;
  const u16* W2b = ws + OFF_W2;
  const int wm = w >> 2, wn = w & 3;
  f32x4 z = {0.f, 0.f, 0.f, 0.f};
  f32x4 acc1[2][4], acc2[2][4];
#pragma unroll
  for (int mi = 0; mi < 2; ++mi)
#pragma unroll
    for (int ni = 0; ni < 4; ++ni) { acc1[mi][ni] = z; acc2[mi][ni] = z; }

  gemm16(acc1, Xb, W0b, 256, lane, wm, wn);            // L1 half 0
  actstore_tanh16(acc1, Hb, pb0, lane, wm, wn);
  __syncthreads();
  gemm16(acc2, Hb, W1b, 512, lane, wm, wn);            // L2 k-slice 0
#pragma unroll
  for (int mi = 0; mi < 2; ++mi)
#pragma unroll
    for (int ni = 0; ni < 4; ++ni) acc1[mi][ni] = z;
  gemm16(acc1, Xb, W0b + 65536, 256, lane, wm, wn);    // L1 half 1
  __syncthreads();
  actstore_tanh16(acc1, Hb, pb0 + 256, lane, wm, wn);
  __syncthreads();
  gemm16(acc2, Hb, W1b + 256, 512, lane, wm, wn);      // L2 k-slice 1
  __syncthreads();

  // residual: r = X + tanh(acc2 + b1) -> Hb (unswizzled)
#pragma unroll
  for (int mi = 0; mi < 2; ++mi)
#pragma unroll
    for (int ni = 0; ni < 4; ++ni)
#pragma unroll
      for (int r = 0; r < 4; ++r) {
        int rl = wm * 32 + mi * 16 + lg * 4 + r;
        int col = wn * 64 + ni * 16 + ll;
        float v = fast_tanh(acc2[mi][ni][r] + pb1[col]);
        int bx = ((rl << 9) + (col << 1)) ^ ((rl & 7) << 4);
        v += bf2f(Xb[bx >> 1]);
        Hb[rl * 256 + col] = f2bf(v);
      }
  __syncthreads();

  // LayerNorm per row -> Hb (swizzled); 8 lanes per row, wave-local
  {
    int row = tid >> 3, jq = tid & 7;
    const u16* hr = Hb + row * 256 + jq * 32;
    bf16x8 chv[4];
#pragma unroll
    for (int q = 0; q < 4; ++q) chv[q] = *(const bf16x8*)(hr + q * 8);
    float s = 0.f, ss = 0.f;
#pragma unroll
    for (int q = 0; q < 4; ++q)
#pragma unroll
      for (int e = 0; e < 8; ++e) { float v = bf2f((u16)chv[q][e]); s += v; ss += v * v; }
    s += __shfl_xor(s, 1);  s += __shfl_xor(s, 2);  s += __shfl_xor(s, 4);
    ss += __shfl_xor(ss, 1); ss += __shfl_xor(ss, 2); ss += __shfl_xor(ss, 4);
    float mu = s * 0.00390625f;
    float var = ss * 0.00390625f - mu * mu;
    float rstd = rsqrtf(var + 1e-5f);
#pragma unroll
    for (int q = 0; q < 4; ++q) {
      bf16x8 o;
#pragma unroll
      for (int e = 0; e < 8; ++e) {
        int col = jq * 32 + q * 8 + e;
        float v = (bf2f((u16)chv[q][e]) - mu) * rstd * pg[col] + pbt[col];
        o[e] = (short)f2bf(v);
      }
      int byt = ((row << 9) + ((jq * 32 + q * 8) << 1)) ^ ((row & 7) << 4);
      *(bf16x8*)(Hb + (byt >> 1)) = o;
    }
  }
  __syncthreads();

  // L3: elu(s2n @ W2^T + b2) -> Xb (unswizzled)
#pragma unroll
  for (int mi = 0; mi < 2; ++mi)
#pragma unroll
    for (int ni = 0; ni < 4; ++ni) acc1[mi][ni] = z;
  gemm16(acc1, Hb, W2b, 256, lane, wm, wn);
#pragma unroll
  for (int mi = 0; mi < 2; ++mi)
#pragma unroll
    for (int ni = 0; ni < 4; ++ni)
#pragma unroll
      for (int r = 0; r < 4; ++r) {
        int rl = wm * 32 + mi * 16 + lg * 4 + r;
        int col = wn * 64 + ni * 16 + ll;
        float v = acc1[mi][ni][r] + pb2[col];
        v = v > 0.f ? v : (__expf(v) - 1.f);
        Xb[rl * 256 + col] = f2bf(v);
      }
  __syncthreads();

  // OS = H3 @ W3^T + b3 ; 8 lanes per row
  {
    int row = tid >> 3, jq = tid & 7;
    const u16* xr = Xb + row * 256 + jq * 32;
    float d0 = 0.f, d1 = 0.f, d2 = 0.f;
#pragma unroll
    for (int q = 0; q < 4; ++q) {
      bf16x8 c = *(const bf16x8*)(xr + q * 8);
#pragma unroll
      for (int e = 0; e < 8; ++e) {
        float v = bf2f((u16)c[e]);
        int col = jq * 32 + q * 8 + e;
        d0 += v * pW3[col]; d1 += v * pW3[256 + col]; d2 += v * pW3[512 + col];
      }
    }
    d0 += __shfl_xor(d0, 1); d0 += __shfl_xor(d0, 2); d0 += __shfl_xor(d0, 4);
    d1 += __shfl_xor(d1, 1); d1 += __shfl_xor(d1, 2); d1 += __shfl_xor(d1, 4);
    d2 += __shfl_xor(d2, 1); d2 += __shfl_xor(d2, 2); d2 += __shfl_xor(d2, 4);
    if (jq == 0) {
      int grow = rt * 128 + row;
      int ob = OS_OFF + t * 3072 + grow * 3;
      out[ob]     = d0 + pb3[0];
      out[ob + 1] = d1 + pb3[1];
      out[ob + 2] = d2 + pb3[2];
    }
  }
}

extern "C" void kernel_launch(void* const* d_in, const int* in_sizes, int n_in,
                              void* d_out, int out_size, void* d_ws, size_t ws_size,
                              hipStream_t stream) {
  const float* KS_ALL  = (const float*)d_in[0];
  const float* next_vf = (const float*)d_in[1];
  const float* A_w     = (const float*)d_in[2];
  const float* B_w     = (const float*)d_in[3];
  const float* W0      = (const float*)d_in[4];
  const float* b0      = (const float*)d_in[5];
  const float* W1      = (const float*)d_in[6];
  const float* b1      = (const float*)d_in[7];
  const float* lng     = (const float*)d_in[8];
  const float* lnb     = (const float*)d_in[9];
  const float* W2      = (const float*)d_in[10];
  const float* b2      = (const float*)d_in[11];
  const float* W3      = (const float*)d_in[12];
  const float* b3      = (const float*)d_in[13];
  u16* ws = (u16*)d_ws;
  float* out = (float*)d_out;

  k_prep<<<4864, 256, 0, stream>>>(KS_ALL, next_vf, A_w, W0, W1, W2, ws);
  for (int s = 1; s <= 32; s <<= 1)
    k_pow<<<dim3(2, s), 512, 0, stream>>>(ws, s);
  k_crevt<<<64, 256, 0, stream>>>(B_w, ws);
  k_fused<<<dim3(8, 513), 1024, 0, stream>>>(ws, b0, b1, lng, lnb, b2, W3, b3, out);
}

// Round 3
// 1499.799 us; speedup vs baseline: 1.3836x; 1.3836x over previous
//
#include <hip/hip_runtime.h>

typedef unsigned short u16;
typedef __attribute__((ext_vector_type(8))) short bf16x8;
typedef __attribute__((ext_vector_type(4))) short bf16x4;
typedef __attribute__((ext_vector_type(4))) float f32x4;

#define MFMA16(a, b, c) __builtin_amdgcn_mfma_f32_16x16x32_bf16((a), (b), (c), 0, 0, 0)

// workspace layout (u16 element offsets)
#define OFF_UPAD 0
#define OFF_KS0  589824
#define OFF_W0   851968
#define OFF_W1   983040
#define OFF_W2   1114112
#define OFF_CRT  1179648
#define OFF_P    1196032     // 65 x 65536 (A^t, t=0..64, row-major, bf16)
#define OS_OFF   134479872   // 513*1024*256

__device__ __forceinline__ u16 f2bf(float f) {
  union { float f; unsigned int i; } v; v.f = f;
  return (u16)((v.i + 0x7fffu + ((v.i >> 16) & 1u)) >> 16);
}
__device__ __forceinline__ float bf2f(u16 u) {
  union { unsigned int i; float f; } v; v.i = ((unsigned int)u) << 16;
  return v.f;
}
__device__ __forceinline__ float fast_tanh(float x) {
  float e = __expf(2.0f * x);
  return 1.0f - __fdividef(2.0f, e + 1.0f);
}

// ---------------- prep: bf16 conversions + P0/P1 ----------------
__global__ void k_prep(const float* __restrict__ KS_ALL, const float* __restrict__ next_vf,
                       const float* __restrict__ A_w, const float* __restrict__ W0,
                       const float* __restrict__ W1, const float* __restrict__ W2,
                       u16* __restrict__ ws) {
  int idx = blockIdx.x * 256 + threadIdx.x;
  if (idx < 589824) {  // u_pad[1024][576]
    int r = idx / 576, c = idx % 576;
    ws[OFF_UPAD + idx] = (c < 64) ? (u16)0 : f2bf(next_vf[r * 512 + c - 64]);
    return;
  }
  idx -= 589824;
  if (idx < 262144) { ws[OFF_KS0 + idx] = f2bf(KS_ALL[idx]); return; }
  idx -= 262144;
  if (idx < 131072) { ws[OFF_W0 + idx] = f2bf(W0[idx]); return; }
  idx -= 131072;
  if (idx < 131072) { ws[OFF_W1 + idx] = f2bf(W1[idx]); return; }
  idx -= 131072;
  if (idx < 65536)  { ws[OFF_W2 + idx] = f2bf(W2[idx]); return; }
  idx -= 65536;
  if (idx < 65536) { // P0 = I, P1 = A
    int r = idx >> 8, c = idx & 255;
    ws[OFF_P + idx] = (r == c) ? (u16)0x3F80 : (u16)0;
    ws[OFF_P + 65536 + idx] = f2bf(A_w[idx]);
  }
}

// ---------------- power doubling ----------------
__global__ __launch_bounds__(512) void k_pow(u16* __restrict__ ws, int s) {
  const u16* P = ws + OFF_P;
  int j = blockIdx.y + 1;
  int mh = blockIdx.x;
  int lane = threadIdx.x & 63, w = threadIdx.x >> 6;
  int wm = w >> 2, wn = w & 3;
  int lg = lane >> 4, ll = lane & 15;
  const u16* Am = P + s * 65536;
  const u16* Bm = P + j * 65536;
  f32x4 acc[4][4];
  f32x4 z = {0.f, 0.f, 0.f, 0.f};
#pragma unroll
  for (int mi = 0; mi < 4; ++mi)
#pragma unroll
    for (int ni = 0; ni < 4; ++ni) acc[mi][ni] = z;
#pragma unroll
  for (int ks = 0; ks < 8; ++ks) {
    bf16x8 a[4], b[4];
    int kk = ks * 32 + lg * 8;
#pragma unroll
    for (int mi = 0; mi < 4; ++mi) {
      int row = mh * 128 + wm * 64 + mi * 16 + ll;
      a[mi] = *(const bf16x8*)(Am + row * 256 + kk);
    }
#pragma unroll
    for (int ni = 0; ni < 4; ++ni) {
      int col = wn * 64 + ni * 16 + ll;
#pragma unroll
      for (int e = 0; e < 8; ++e) b[ni][e] = (short)Bm[(kk + e) * 256 + col];
    }
#pragma unroll
    for (int mi = 0; mi < 4; ++mi)
#pragma unroll
      for (int ni = 0; ni < 4; ++ni) acc[mi][ni] = MFMA16(a[mi], b[ni], acc[mi][ni]);
  }
  u16* Pd = ws + OFF_P + (s + j) * 65536;
#pragma unroll
  for (int mi = 0; mi < 4; ++mi)
#pragma unroll
    for (int ni = 0; ni < 4; ++ni)
#pragma unroll
      for (int r = 0; r < 4; ++r) {
        int row = mh * 128 + wm * 64 + mi * 16 + lg * 4 + r;
        int col = wn * 64 + ni * 16 + ll;
        Pd[row * 256 + col] = f2bf(acc[mi][ni][r]);
      }
}

// ---------------- CrevT[n][s] = c_{63-s}[n] ----------------
__global__ void k_crevt(const float* __restrict__ B_w, u16* __restrict__ ws) {
  int s = blockIdx.x;
  int n = threadIdx.x;
  const u16* Pr = ws + OFF_P + (63 - s) * 65536 + n * 256;
  float acc = 0.f;
  for (int k = 0; k < 256; ++k) acc += bf2f(Pr[k]) * B_w[k];
  ws[OFF_CRT + n * 64 + s] = f2bf(acc);
}

// ---------------- fused KS-gen + MLP: BM=64 rows, 512 thr, 8 waves ----------------
// Wave tile 64x32 everywhere: acc[4][2] = 32 VGPR, single-live accumulator.
__global__ __launch_bounds__(512, 1) void k_fused(
    const u16* __restrict__ ws,
    const float* __restrict__ b0, const float* __restrict__ b1,
    const float* __restrict__ lng, const float* __restrict__ lnb,
    const float* __restrict__ b2, const float* __restrict__ W3,
    const float* __restrict__ b3, float* __restrict__ out) {
  __shared__ __align__(16) u16 Xb[16384];             // 64x256 bf16, XOR-swz (512B row stride)
  __shared__ __align__(16) unsigned char Hraw[66560]; // CrevT stage / f32 [64][260] / H1 64x512 bf16
  __shared__ float par[2308];
  u16* Hb = (u16*)Hraw;
  float* Hf = (float*)Hraw;

  float* pb0 = par;          // 512
  float* pb1 = par + 512;    // 256
  float* pg  = par + 768;    // 256
  float* pbt = par + 1024;   // 256
  float* pb2 = par + 1280;   // 256
  float* pW3 = par + 1536;   // 768
  float* pb3 = par + 2304;   // 4

  const int t  = blockIdx.y;        // 0..512
  const int R0 = blockIdx.x * 64;   // row base
  const int tid = threadIdx.x;
  const int lane = tid & 63, w = tid >> 6;
  const int lg = lane >> 4, ll = lane & 15;

  pb0[tid] = b0[tid];
  if (tid < 256) { pb1[tid] = b1[tid]; pg[tid] = lng[tid]; pbt[tid] = lnb[tid]; pb2[tid] = b2[tid]; }
  pW3[tid < 512 ? tid : 0] = W3[tid < 512 ? tid : 0];
  if (tid < 256) pW3[512 + tid] = W3[512 + tid];
  if (tid < 4) pb3[tid] = (tid < 3) ? b3[tid] : 0.f;

  // stage CrevT (256 n x 64 s bf16, 128B row stride) swizzled into Hb
  {
    const u16* src = ws + OFF_CRT;
#pragma unroll
    for (int c = 0; c < 4; ++c) {
      int cid = c * 512 + tid;
      int n = cid >> 3, q = cid & 7;
      bf16x8 v = *(const bf16x8*)(src + n * 64 + q * 8);
      int byt = ((n << 7) + (q << 4)) ^ ((n & 7) << 4);
      *(bf16x8*)(Hb + (byt >> 1)) = v;
    }
  }
  __syncthreads();

  f32x4 z = {0.f, 0.f, 0.f, 0.f};

  // ---- phase 1: KS_pre rows R0..R0+63, wave w covers cols w*32..+31 ----
  f32x4 acc[4][2];
#pragma unroll
  for (int mi = 0; mi < 4; ++mi)
#pragma unroll
    for (int ni = 0; ni < 2; ++ni) acc[mi][ni] = z;
  {
    // u-window A fragments: rows R0+mi*16+ll, k = ksu*32+lg*8
    bf16x8 au[4][2];
#pragma unroll
    for (int mi = 0; mi < 4; ++mi)
#pragma unroll
      for (int ksu = 0; ksu < 2; ++ksu) {
        const u16* up = ws + OFF_UPAD + (R0 + mi * 16 + ll) * 576 + t + ksu * 32 + lg * 8;
#pragma unroll
        for (int e = 0; e < 8; ++e) au[mi][ksu][e] = (short)up[e];
      }
#pragma unroll
    for (int ksu = 0; ksu < 2; ++ksu)
#pragma unroll
      for (int ni = 0; ni < 2; ++ni) {
        int n = w * 32 + ni * 16 + ll;
        int byt = ((n << 7) + ksu * 64 + (lg << 4)) ^ ((n & 7) << 4);
        bf16x8 bfr = *(const bf16x8*)(Hb + (byt >> 1));
#pragma unroll
        for (int mi = 0; mi < 4; ++mi) acc[mi][ni] = MFMA16(au[mi][ksu], bfr, acc[mi][ni]);
      }
    if (t < 64) {
      const u16* Pt = ws + OFF_P + t * 65536;
      const u16* ks0b = ws + OFF_KS0;
#pragma unroll
      for (int ks = 0; ks < 8; ++ks) {
        bf16x8 a[4], b[2];
#pragma unroll
        for (int mi = 0; mi < 4; ++mi)
          a[mi] = *(const bf16x8*)(ks0b + (R0 + mi * 16 + ll) * 256 + ks * 32 + lg * 8);
#pragma unroll
        for (int ni = 0; ni < 2; ++ni)
          b[ni] = *(const bf16x8*)(Pt + (w * 32 + ni * 16 + ll) * 256 + ks * 32 + lg * 8);
#pragma unroll
        for (int mi = 0; mi < 4; ++mi)
#pragma unroll
          for (int ni = 0; ni < 2; ++ni) acc[mi][ni] = MFMA16(a[mi], b[ni], acc[mi][ni]);
      }
    }
  }
  __syncthreads();  // CrevT reads done; Hraw becomes f32 bounce

  // f32 bounce [64][260]
#pragma unroll
  for (int mi = 0; mi < 4; ++mi)
#pragma unroll
    for (int ni = 0; ni < 2; ++ni)
#pragma unroll
      for (int r = 0; r < 4; ++r)
        Hf[(mi * 16 + lg * 4 + r) * 260 + w * 32 + ni * 16 + ll] = acc[mi][ni][r];
  __syncthreads();

  // coalesced nontemporal KS store + Xb build
  {
    float* ob = out + (size_t)t * 262144 + (size_t)R0 * 256;
#pragma unroll
    for (int it = 0; it < 8; ++it) {
      int idx = it * 512 + tid;
      int row = idx >> 6, c4 = idx & 63;
      f32x4 v = *(const f32x4*)(Hf + row * 260 + c4 * 4);
      __builtin_nontemporal_store(v, (f32x4*)(ob + row * 256 + c4 * 4));
      bf16x4 h;
#pragma unroll
      for (int e = 0; e < 4; ++e) h[e] = (short)f2bf(v[e]);
      int byt = (((row << 9) + ((c4 >> 1) << 4)) ^ ((row & 7) << 4)) + ((c4 & 1) << 3);
      *(bf16x4*)(Xb + (byt >> 1)) = h;
    }
  }
  __syncthreads();  // Hraw becomes H1 (64x512 bf16, 1024B row stride, swz)

  // ---- L1: H1 = tanh(X @ W0^T + b0), two col-halves, single acc ----
  const u16* W0b = ws + OFF_W0;
#pragma unroll 1
  for (int h = 0; h < 2; ++h) {
#pragma unroll
    for (int mi = 0; mi < 4; ++mi)
#pragma unroll
      for (int ni = 0; ni < 2; ++ni) acc[mi][ni] = z;
#pragma unroll
    for (int ks = 0; ks < 8; ++ks) {
      bf16x8 a[4], b[2];
#pragma unroll
      for (int mi = 0; mi < 4; ++mi) {
        int rl = mi * 16 + ll;
        int byt = ((rl << 9) + ks * 64 + (lg << 4)) ^ ((rl & 7) << 4);
        a[mi] = *(const bf16x8*)(Xb + (byt >> 1));
      }
#pragma unroll
      for (int ni = 0; ni < 2; ++ni) {
        int n = h * 256 + w * 32 + ni * 16 + ll;
        b[ni] = *(const bf16x8*)(W0b + n * 256 + ks * 32 + lg * 8);
      }
#pragma unroll
      for (int mi = 0; mi < 4; ++mi)
#pragma unroll
        for (int ni = 0; ni < 2; ++ni) acc[mi][ni] = MFMA16(a[mi], b[ni], acc[mi][ni]);
    }
#pragma unroll
    for (int mi = 0; mi < 4; ++mi)
#pragma unroll
      for (int ni = 0; ni < 2; ++ni)
#pragma unroll
        for (int r = 0; r < 4; ++r) {
          int rl = mi * 16 + lg * 4 + r;
          int col = h * 256 + w * 32 + ni * 16 + ll;
          float v = fast_tanh(acc[mi][ni][r] + pb0[col]);
          int byt = ((rl << 10) + (col << 1)) ^ ((rl & 7) << 4);
          Hb[byt >> 1] = f2bf(v);
        }
  }
  __syncthreads();

  // ---- L2: acc = H1 @ W1^T (K=512), then residual + tanh ----
#pragma unroll
  for (int mi = 0; mi < 4; ++mi)
#pragma unroll
    for (int ni = 0; ni < 2; ++ni) acc[mi][ni] = z;
  {
    const u16* W1b = ws + OFF_W1;
#pragma unroll
    for (int ks = 0; ks < 16; ++ks) {
      bf16x8 a[4], b[2];
#pragma unroll
      for (int mi = 0; mi < 4; ++mi) {
        int rl = mi * 16 + ll;
        int byt = ((rl << 10) + ks * 64 + (lg << 4)) ^ ((rl & 7) << 4);
        a[mi] = *(const bf16x8*)(Hb + (byt >> 1));
      }
#pragma unroll
      for (int ni = 0; ni < 2; ++ni) {
        int n = w * 32 + ni * 16 + ll;
        b[ni] = *(const bf16x8*)(W1b + n * 512 + ks * 32 + lg * 8);
      }
#pragma unroll
      for (int mi = 0; mi < 4; ++mi)
#pragma unroll
        for (int ni = 0; ni < 2; ++ni) acc[mi][ni] = MFMA16(a[mi], b[ni], acc[mi][ni]);
    }
  }
  __syncthreads();  // all H1 reads done; Hb becomes residual [64][256] unswz

#pragma unroll
  for (int mi = 0; mi < 4; ++mi)
#pragma unroll
    for (int ni = 0; ni < 2; ++ni)
#pragma unroll
      for (int r = 0; r < 4; ++r) {
        int rl = mi * 16 + lg * 4 + r;
        int col = w * 32 + ni * 16 + ll;
        float v = fast_tanh(acc[mi][ni][r] + pb1[col]);
        int bx = ((rl << 9) + (col << 1)) ^ ((rl & 7) << 4);
        v += bf2f(Xb[bx >> 1]);
        Hb[rl * 256 + col] = f2bf(v);
      }
  __syncthreads();

  // ---- LayerNorm per row, in place -> swizzled (512B row stride) ----
  {
    int row = tid >> 3, jq = tid & 7;
    const u16* hr = Hb + row * 256 + jq * 32;
    bf16x8 chv[4];
#pragma unroll
    for (int q = 0; q < 4; ++q) chv[q] = *(const bf16x8*)(hr + q * 8);
    float s = 0.f, ss = 0.f;
#pragma unroll
    for (int q = 0; q < 4; ++q)
#pragma unroll
      for (int e = 0; e < 8; ++e) { float v = bf2f((u16)chv[q][e]); s += v; ss += v * v; }
    s += __shfl_xor(s, 1);  s += __shfl_xor(s, 2);  s += __shfl_xor(s, 4);
    ss += __shfl_xor(ss, 1); ss += __shfl_xor(ss, 2); ss += __shfl_xor(ss, 4);
    float mu = s * 0.00390625f;
    float var = ss * 0.00390625f - mu * mu;
    float rstd = rsqrtf(var + 1e-5f);
#pragma unroll
    for (int q = 0; q < 4; ++q) {
      bf16x8 o;
#pragma unroll
      for (int e = 0; e < 8; ++e) {
        int col = jq * 32 + q * 8 + e;
        float v = (bf2f((u16)chv[q][e]) - mu) * rstd * pg[col] + pbt[col];
        o[e] = (short)f2bf(v);
      }
      int byt = ((row << 9) + ((jq * 32 + q * 8) << 1)) ^ ((row & 7) << 4);
      *(bf16x8*)(Hb + (byt >> 1)) = o;
    }
  }
  __syncthreads();

  // ---- L3: elu(s2n @ W2^T + b2) -> Xb unswz ----
#pragma unroll
  for (int mi = 0; mi < 4; ++mi)
#pragma unroll
    for (int ni = 0; ni < 2; ++ni) acc[mi][ni] = z;
  {
    const u16* W2b = ws + OFF_W2;
#pragma unroll
    for (int ks = 0; ks < 8; ++ks) {
      bf16x8 a[4], b[2];
#pragma unroll
      for (int mi = 0; mi < 4; ++mi) {
        int rl = mi * 16 + ll;
        int byt = ((rl << 9) + ks * 64 + (lg << 4)) ^ ((rl & 7) << 4);
        a[mi] = *(const bf16x8*)(Hb + (byt >> 1));
      }
#pragma unroll
      for (int ni = 0; ni < 2; ++ni) {
        int n = w * 32 + ni * 16 + ll;
        b[ni] = *(const bf16x8*)(W2b + n * 256 + ks * 32 + lg * 8);
      }
#pragma unroll
      for (int mi = 0; mi < 4; ++mi)
#pragma unroll
        for (int ni = 0; ni < 2; ++ni) acc[mi][ni] = MFMA16(a[mi], b[ni], acc[mi][ni]);
    }
  }
#pragma unroll
  for (int mi = 0; mi < 4; ++mi)
#pragma unroll
    for (int ni = 0; ni < 2; ++ni)
#pragma unroll
      for (int r = 0; r < 4; ++r) {
        int rl = mi * 16 + lg * 4 + r;
        int col = w * 32 + ni * 16 + ll;
        float v = acc[mi][ni][r] + pb2[col];
        v = v > 0.f ? v : (__expf(v) - 1.f);
        Xb[rl * 256 + col] = f2bf(v);
      }
  __syncthreads();

  // ---- OS = H3 @ W3^T + b3 ----
  {
    int row = tid >> 3, jq = tid & 7;
    const u16* xr = Xb + row * 256 + jq * 32;
    float d0 = 0.f, d1 = 0.f, d2 = 0.f;
#pragma unroll
    for (int q = 0; q < 4; ++q) {
      bf16x8 c = *(const bf16x8*)(xr + q * 8);
#pragma unroll
      for (int e = 0; e < 8; ++e) {
        float v = bf2f((u16)c[e]);
        int col = jq * 32 + q * 8 + e;
        d0 += v * pW3[col]; d1 += v * pW3[256 + col]; d2 += v * pW3[512 + col];
      }
    }
    d0 += __shfl_xor(d0, 1); d0 += __shfl_xor(d0, 2); d0 += __shfl_xor(d0, 4);
    d1 += __shfl_xor(d1, 1); d1 += __shfl_xor(d1, 2); d1 += __shfl_xor(d1, 4);
    d2 += __shfl_xor(d2, 1); d2 += __shfl_xor(d2, 2); d2 += __shfl_xor(d2, 4);
    if (jq == 0) {
      int grow = R0 + row;
      int ob = OS_OFF + t * 3072 + grow * 3;
      out[ob]     = d0 + pb3[0];
      out[ob + 1] = d1 + pb3[1];
      out[ob + 2] = d2 + pb3[2];
    }
  }
}

extern "C" void kernel_launch(void* const* d_in, const int* in_sizes, int n_in,
                              void* d_out, int out_size, void* d_ws, size_t ws_size,
                              hipStream_t stream) {
  const float* KS_ALL  = (const float*)d_in[0];
  const float* next_vf = (const float*)d_in[1];
  const float* A_w     = (const float*)d_in[2];
  const float* B_w     = (const float*)d_in[3];
  const float* W0      = (const float*)d_in[4];
  const float* b0      = (const float*)d_in[5];
  const float* W1      = (const float*)d_in[6];
  const float* b1      = (const float*)d_in[7];
  const float* lng     = (const float*)d_in[8];
  const float* lnb     = (const float*)d_in[9];
  const float* W2      = (const float*)d_in[10];
  const float* b2      = (const float*)d_in[11];
  const float* W3      = (const float*)d_in[12];
  const float* b3      = (const float*)d_in[13];
  u16* ws = (u16*)d_ws;
  float* out = (float*)d_out;

  k_prep<<<4864, 256, 0, stream>>>(KS_ALL, next_vf, A_w, W0, W1, W2, ws);
  for (int s = 1; s <= 32; s <<= 1)
    k_pow<<<dim3(2, s), 512, 0, stream>>>(ws, s);
  k_crevt<<<64, 256, 0, stream>>>(B_w, ws);
  k_fused<<<dim3(16, 513), 512, 0, stream>>>(ws, b0, b1, lng, lnb, b2, W3, b3, out);
}